// Round 11
// baseline (19.800 us; speedup 1.0000x reference)
//
#include <hip/hip_runtime.h>

// RefinementCAM: B=4, C=256, H=W=64, N=4096.
// out[b,n] = s[b,n] * (feat[b,:,n] . v[b,:]),
//   v[b,c] = sum_m feat[b,c,m] * w[b,m],  w = s*cam,
//   s = m/max(m*||feat[:,n]||,1e-12),  m in {0,1/3,2/3,1}.
// R7 4-node skeleton; K1/K3 at 512 threads/block (16 waves/CU, was 8) to
// deepen latency hiding on the feat passes. K2/K4 unchanged (proven).

constexpr int B    = 4;
constexpr int C    = 256;
constexpr int N    = 4096;
constexpr int BN   = B * N;       // 16384
constexpr int CN   = C * N;
constexpr int NBLK = 512;         // 32 pixels per block

#define SCOPE_AGENT __HIP_MEMORY_SCOPE_AGENT

__device__ __forceinline__ float wsum(float v) {
#pragma unroll
    for (int o = 32; o > 0; o >>= 1) v += __shfl_down(v, o, 64);
    return v;
}
__device__ __forceinline__ float wmin64(float v) {
#pragma unroll
    for (int o = 32; o > 0; o >>= 1) v = fminf(v, __shfl_down(v, o, 64));
    return v;
}
__device__ __forceinline__ float wmax64(float v) {
#pragma unroll
    for (int o = 32; o > 0; o >>= 1) v = fmaxf(v, __shfl_down(v, o, 64));
    return v;
}

// K1: 512 blocks x 512 thr (8 waves). Thread=(G=t>>3 in 0..63, qu=t&7):
// 4x float4 cold coalesced loads (channels it*64+G, pixels qu*4..+3) ->
// registers; per-pixel norms via red4; v-partials via 8-lane shfl.
__global__ void __launch_bounds__(512) k_norm_vpart(
    const float* __restrict__ cam, const float* __restrict__ feat,
    float* __restrict__ s, float* __restrict__ v_part,
    unsigned int* __restrict__ cnt)
{
    if (blockIdx.x == 0 && threadIdx.x == 0) *cnt = 0u;

    __shared__ float red4[64][33];   // [G][pix]; stride 33 -> <=2-way alias
    __shared__ float w_sh[32];

    const int t  = threadIdx.x;      // 0..511
    const int qu = t & 7;            // pixel quad (4 consecutive pixels)
    const int G  = t >> 3;           // channel selector 0..63
    const int bk = blockIdx.x;
    const int b  = bk >> 7;          // 128 blocks per batch
    const int n0 = (bk * 32) & (N - 1);

    const float* fp = feat + (size_t)b * CN + n0 + qu * 4;
    float4 x[4];
    float4 ss = make_float4(0.f, 0.f, 0.f, 0.f);
#pragma unroll
    for (int it = 0; it < 4; ++it) {
        x[it] = *(const float4*)(fp + (size_t)(it * 64 + G) * N);
        ss.x = fmaf(x[it].x, x[it].x, ss.x);
        ss.y = fmaf(x[it].y, x[it].y, ss.y);
        ss.z = fmaf(x[it].z, x[it].z, ss.z);
        ss.w = fmaf(x[it].w, x[it].w, ss.w);
    }
    red4[G][qu * 4 + 0] = ss.x;
    red4[G][qu * 4 + 1] = ss.y;
    red4[G][qu * 4 + 2] = ss.z;
    red4[G][qu * 4 + 3] = ss.w;
    __syncthreads();

    if (t < 32) {
        float tot = 0.f;
#pragma unroll
        for (int g = 0; g < 64; ++g) tot += red4[g][t];   // odd stride: free
        float cv = cam[bk * 32 + t];
        float m  = ((cv >= 0.3f ? 1.f : 0.f) + (cv >= 0.4f ? 1.f : 0.f) +
                    (cv >= 0.5f ? 1.f : 0.f)) * (1.f / 3.f);
        float sc = m / fmaxf(m * sqrtf(tot), 1e-12f);     // ||feat*m|| = m*||feat||
        s[bk * 32 + t] = sc;
        w_sh[t] = sc * cv;
    }
    __syncthreads();

    float4 wq = *(const float4*)&w_sh[qu * 4];
    float vp[4];
#pragma unroll
    for (int it = 0; it < 4; ++it) {
        float a = fmaf(x[it].x, wq.x,
                  fmaf(x[it].y, wq.y,
                  fmaf(x[it].z, wq.z, x[it].w * wq.w)));
#pragma unroll
        for (int o = 4; o > 0; o >>= 1) a += __shfl_down(a, o, 8);
        vp[it] = a;
    }
    if (qu == 0) {
#pragma unroll
        for (int it = 0; it < 4; ++it)
            v_part[bk * 256 + it * 64 + G] = vp[it];      // plain coalesced
    }
}

// K2: 16 blocks x 256 thr (unchanged). v[bc] = sum of 128 partials, 4-way split-k.
__global__ void __launch_bounds__(256) k_vreduce(
    const float* __restrict__ v_part, float* __restrict__ v)
{
    __shared__ float vred[4][64];
    const int t  = threadIdx.x;
    const int l  = t & 63;
    const int ks = t >> 6;
    const int bc = blockIdx.x * 64 + l;          // 0..1023
    const int vb = bc >> 8, c = bc & 255;
    const float* vp = v_part + (size_t)vb * (128 * 256) + c;
    float a = 0.f;
#pragma unroll
    for (int kk = 0; kk < 32; ++kk)
        a += vp[(size_t)(ks * 32 + kk) * 256];   // coalesced across lanes
    vred[ks][l] = a;
    __syncthreads();
    if (t < 64)
        v[bc] = (vred[0][t] + vred[1][t]) + (vred[2][t] + vred[3][t]);
}

// K3: 512 blocks x 512 thr. Same mapping as K1; ob = s*(feat[:,n].v);
// block min/max. feat is L3-hot from K1.
__global__ void __launch_bounds__(512) k_out(
    const float* __restrict__ feat, const float* __restrict__ s,
    const float* __restrict__ v, float* __restrict__ ob,
    float* __restrict__ bmn, float* __restrict__ bmx)
{
    __shared__ float vs[C];
    __shared__ float red4[64][33];

    const int t  = threadIdx.x;
    const int qu = t & 7;
    const int G  = t >> 3;
    const int bk = blockIdx.x;
    const int b  = bk >> 7;
    const int n0 = (bk * 32) & (N - 1);

    if (t < C) vs[t] = v[b * C + t];
    __syncthreads();

    const float* fp = feat + (size_t)b * CN + n0 + qu * 4;
    float4 acc = make_float4(0.f, 0.f, 0.f, 0.f);
#pragma unroll
    for (int it = 0; it < 4; ++it) {
        float4 xx = *(const float4*)(fp + (size_t)(it * 64 + G) * N);
        float vc = vs[it * 64 + G];              // 8-lane same-addr broadcast
        acc.x = fmaf(xx.x, vc, acc.x);
        acc.y = fmaf(xx.y, vc, acc.y);
        acc.z = fmaf(xx.z, vc, acc.z);
        acc.w = fmaf(xx.w, vc, acc.w);
    }
    red4[G][qu * 4 + 0] = acc.x;
    red4[G][qu * 4 + 1] = acc.y;
    red4[G][qu * 4 + 2] = acc.z;
    red4[G][qu * 4 + 3] = acc.w;
    __syncthreads();

    if (t < 32) {
        float tot = 0.f;
#pragma unroll
        for (int g = 0; g < 64; ++g) tot += red4[g][t];
        float o = s[bk * 32 + t] * tot;
        ob[bk * 32 + t] = o;
        float mn = o, mx = o;
#pragma unroll
        for (int o2 = 16; o2 > 0; o2 >>= 1) {
            mn = fminf(mn, __shfl_down(mn, o2, 64));
            mx = fmaxf(mx, __shfl_down(mx, o2, 64));
        }
        if (t == 0) { bmn[bk] = mn; bmx[bk] = mx; }
    }
}

// K4: 64 blocks x 256 thr (unchanged, proven). Batch minmax, rescale,
// |ref-cam|; last block finishes loss with fixed-order (deterministic) sum.
__global__ void __launch_bounds__(256) k_final(
    const float* __restrict__ ob, const float* __restrict__ cam,
    const float* __restrict__ bmn, const float* __restrict__ bmx,
    float* __restrict__ out, float* __restrict__ part, unsigned int* __restrict__ cnt)
{
    const int t = threadIdx.x, blk = blockIdx.x;
    const int p = blk * 256 + t;
    const int b = blk >> 4;                 // 16 blocks per batch

    __shared__ float sh[2];
    if (t < 64) {
        float a = fminf(bmn[b * 128 + t], bmn[b * 128 + 64 + t]);
        a = wmin64(a);
        if (t == 0) sh[0] = a;
    } else if (t < 128) {
        int l = t - 64;
        float a = fmaxf(bmx[b * 128 + l], bmx[b * 128 + 64 + l]);
        a = wmax64(a);
        if (l == 0) sh[1] = a;
    }
    __syncthreads();
    const float mn = sh[0];
    const float mx = sh[1] + 1e-5f;

    float r = (ob[p] - mn) / (mx - mn);
    out[p] = r;
    float ad = fabsf(r - cam[p]);

    __shared__ float red[4];
    float ps = wsum(ad);
    if ((t & 63) == 0) red[t >> 6] = ps;
    __syncthreads();

    __shared__ int lastflag;
    if (t == 0) {
        float tot = (red[0] + red[1]) + (red[2] + red[3]);
        __hip_atomic_store(&part[blk], tot, __ATOMIC_RELEASE, SCOPE_AGENT);
        unsigned old = __hip_atomic_fetch_add(cnt, 1u, __ATOMIC_ACQ_REL, SCOPE_AGENT);
        lastflag = (old == 63u) ? 1 : 0;
    }
    __syncthreads();
    if (lastflag && t < 64) {
        float x = __hip_atomic_load(&part[t], __ATOMIC_ACQUIRE, SCOPE_AGENT);
        x = wsum(x);                        // fixed-order: deterministic
        if (t == 0) out[BN] = x * (1.f / (float)BN);
    }
}

extern "C" void kernel_launch(void* const* d_in, const int* in_sizes, int n_in,
                              void* d_out, int out_size, void* d_ws, size_t ws_size,
                              hipStream_t stream) {
    const float* cam  = (const float*)d_in[0];   // (4,64,64)
    const float* feat = (const float*)d_in[1];   // (4,256,64,64)
    float* out = (float*)d_out;                  // [16384 ref][1 loss]
    float* ws  = (float*)d_ws;

    float* s      = ws;                   // 16384
    float* v_part = ws + 16384;           // 512*256 = 131072
    float* v      = ws + 147456;          // 1024
    float* ob     = ws + 148480;          // 16384
    float* bmn    = ws + 164864;          // 512
    float* bmx    = ws + 165376;          // 512
    float* part   = ws + 165888;          // 64
    unsigned int* cnt = (unsigned int*)(ws + 165952);

    k_norm_vpart<<<NBLK, 512, 0, stream>>>(cam, feat, s, v_part, cnt);
    k_vreduce   <<<16,   256, 0, stream>>>(v_part, v);
    k_out       <<<NBLK, 512, 0, stream>>>(feat, s, v, ob, bmn, bmx);
    k_final     <<<64,   256, 0, stream>>>(ob, cam, bmn, bmx, out, part, cnt);
}

// Round 12
// 18.895 us; speedup vs baseline: 1.0479x; 1.0479x over previous
//
#include <hip/hip_runtime.h>

// RefinementCAM: B=4, C=256, H=W=64, N=4096.
// out[b,n] = s[b,n] * (feat[b,:,n] . v[b,:]),
//   v[b,c] = sum_m feat[b,c,m] * w[b,m],  w = s*cam,
//   s = m/max(m*||feat[:,n]||,1e-12),  m in {0,1/3,2/3,1}.
// FINAL (revert to R7 best, 18.90 us): 4 kernels, pure kernel-boundary
// dataflow; K1 stashes its feat tile in padded LDS so v needs no second
// feat pass; cross-block sync only via tiny agent-scope atomics in K4.

constexpr int B    = 4;
constexpr int C    = 256;
constexpr int N    = 4096;
constexpr int BN   = B * N;       // 16384
constexpr int CN   = C * N;
constexpr int NBLK = 512;         // K1/K3 blocks (32 pixels each)

#define SCOPE_AGENT __HIP_MEMORY_SCOPE_AGENT

__device__ __forceinline__ float wsum(float v) {
#pragma unroll
    for (int o = 32; o > 0; o >>= 1) v += __shfl_down(v, o, 64);
    return v;
}
__device__ __forceinline__ float wmin64(float v) {
#pragma unroll
    for (int o = 32; o > 0; o >>= 1) v = fminf(v, __shfl_down(v, o, 64));
    return v;
}
__device__ __forceinline__ float wmax64(float v) {
#pragma unroll
    for (int o = 32; o > 0; o >>= 1) v = fmaxf(v, __shfl_down(v, o, 64));
    return v;
}

// K1: 512 blocks x 256 thr. Cold coalesced read of the block's 256x32 feat
// tile; norm accumulate while stashing in padded LDS; v-partials from LDS.
// Plain stores only (kernel boundary = visibility). Zeroes k_final's counter.
__global__ void __launch_bounds__(256) k_norm_vpart(
    const float* __restrict__ cam, const float* __restrict__ feat,
    float* __restrict__ s, float* __restrict__ v_part,
    unsigned int* __restrict__ cnt)
{
    if (blockIdx.x == 0 && threadIdx.x == 0) *cnt = 0u;

    __shared__ float tile[C * 33];   // [c][pix], stride 33: 2-way alias = free
    __shared__ float red[8][33];
    __shared__ float w_sh[32];

    const int t   = threadIdx.x;
    const int pix = t & 31;
    const int g   = t >> 5;          // channel group 0..7
    const int bk  = blockIdx.x;
    const int b   = bk >> 7;         // 128 blocks per batch
    const int n0  = (bk * 32) & (N - 1);

    {
        const float* fp = feat + (size_t)b * CN + (size_t)(g * 32) * N + n0 + pix;
        float ss = 0.f;
#pragma unroll
        for (int cc = 0; cc < 32; ++cc) {
            float x = fp[(size_t)cc * N];            // 32-lane contiguous
            ss = fmaf(x, x, ss);
            tile[(g * 32 + cc) * 33 + pix] = x;
        }
        red[g][pix] = ss;
    }
    __syncthreads();
    if (t < 32) {
        float tot = 0.f;
#pragma unroll
        for (int gg = 0; gg < 8; ++gg) tot += red[gg][t];
        float cv = cam[bk * 32 + t];
        float m  = ((cv >= 0.3f ? 1.f : 0.f) + (cv >= 0.4f ? 1.f : 0.f) +
                    (cv >= 0.5f ? 1.f : 0.f)) * (1.f / 3.f);
        float sc = m / fmaxf(m * sqrtf(tot), 1e-12f);  // ||feat*m|| = m*||feat||
        s[bk * 32 + t] = sc;
        w_sh[t] = sc * cv;
    }
    __syncthreads();
    {
        float acc = 0.f;
#pragma unroll
        for (int pp = 0; pp < 32; ++pp)
            acc = fmaf(tile[t * 33 + pp], w_sh[pp], acc);   // stride-33: conflict-free
        v_part[bk * 256 + t] = acc;                  // coalesced plain store
    }
}

// K2: 16 blocks x 256 thr. v[bc] = sum of 128 block-partials (4-way split-k).
__global__ void __launch_bounds__(256) k_vreduce(
    const float* __restrict__ v_part, float* __restrict__ v)
{
    __shared__ float vred[4][64];
    const int t  = threadIdx.x;
    const int l  = t & 63;
    const int ks = t >> 6;                       // split-k 0..3
    const int bc = blockIdx.x * 64 + l;          // 0..1023
    const int vb = bc >> 8, c = bc & 255;
    const float* vp = v_part + (size_t)vb * (128 * 256) + c;
    float a = 0.f;
#pragma unroll
    for (int kk = 0; kk < 32; ++kk)
        a += vp[(size_t)(ks * 32 + kk) * 256];   // coalesced across lanes
    vred[ks][l] = a;
    __syncthreads();
    if (t < 64)
        v[bc] = (vred[0][t] + vred[1][t]) + (vred[2][t] + vred[3][t]);
}

// K3: 512 blocks x 256 thr. ob = s*(feat[:,n].v); block min/max.
__global__ void __launch_bounds__(256) k_out(
    const float* __restrict__ feat, const float* __restrict__ s,
    const float* __restrict__ v, float* __restrict__ ob,
    float* __restrict__ bmn, float* __restrict__ bmx)
{
    const int t   = threadIdx.x;
    const int pix = t & 31;
    const int g   = t >> 5;
    const int bk  = blockIdx.x;
    const int b   = bk >> 7;
    const int n0  = (bk * 32) & (N - 1);

    __shared__ float vs[C];
    vs[t] = v[b * C + t];
    __syncthreads();

    const float* fp = feat + (size_t)b * CN + (size_t)(g * 32) * N + n0 + pix;
    float acc = 0.f;
#pragma unroll 8
    for (int cc = 0; cc < 32; ++cc)
        acc = fmaf(fp[(size_t)cc * N], vs[g * 32 + cc], acc);  // vs broadcast

    __shared__ float red[8][33];
    red[g][pix] = acc;
    __syncthreads();
    if (t < 32) {
        float tot = 0.f;
#pragma unroll
        for (int gg = 0; gg < 8; ++gg) tot += red[gg][t];
        float o = s[bk * 32 + t] * tot;
        ob[bk * 32 + t] = o;
        float mn = o, mx = o;
#pragma unroll
        for (int o2 = 16; o2 > 0; o2 >>= 1) {
            mn = fminf(mn, __shfl_down(mn, o2, 64));
            mx = fmaxf(mx, __shfl_down(mx, o2, 64));
        }
        if (t == 0) { bmn[bk] = mn; bmx[bk] = mx; }
    }
}

// K4: 64 blocks x 256 thr. Batch minmax, rescale, |ref-cam|; last block
// finishes the loss with a fixed-order (deterministic) sum.
__global__ void __launch_bounds__(256) k_final(
    const float* __restrict__ ob, const float* __restrict__ cam,
    const float* __restrict__ bmn, const float* __restrict__ bmx,
    float* __restrict__ out, float* __restrict__ part, unsigned int* __restrict__ cnt)
{
    const int t = threadIdx.x, blk = blockIdx.x;
    const int p = blk * 256 + t;
    const int b = blk >> 4;                 // 16 blocks per batch

    __shared__ float sh[2];
    if (t < 64) {
        float a = fminf(bmn[b * 128 + t], bmn[b * 128 + 64 + t]);
        a = wmin64(a);
        if (t == 0) sh[0] = a;
    } else if (t < 128) {
        int l = t - 64;
        float a = fmaxf(bmx[b * 128 + l], bmx[b * 128 + 64 + l]);
        a = wmax64(a);
        if (l == 0) sh[1] = a;
    }
    __syncthreads();
    const float mn = sh[0];
    const float mx = sh[1] + 1e-5f;

    float r = (ob[p] - mn) / (mx - mn);
    out[p] = r;
    float ad = fabsf(r - cam[p]);

    __shared__ float red[4];
    float ps = wsum(ad);
    if ((t & 63) == 0) red[t >> 6] = ps;
    __syncthreads();

    __shared__ int lastflag;
    if (t == 0) {
        float tot = (red[0] + red[1]) + (red[2] + red[3]);
        __hip_atomic_store(&part[blk], tot, __ATOMIC_RELEASE, SCOPE_AGENT);
        unsigned old = __hip_atomic_fetch_add(cnt, 1u, __ATOMIC_ACQ_REL, SCOPE_AGENT);
        lastflag = (old == 63u) ? 1 : 0;
    }
    __syncthreads();
    if (lastflag && t < 64) {
        float x = __hip_atomic_load(&part[t], __ATOMIC_ACQUIRE, SCOPE_AGENT);
        x = wsum(x);                        // fixed-order: deterministic
        if (t == 0) out[BN] = x * (1.f / (float)BN);
    }
}

extern "C" void kernel_launch(void* const* d_in, const int* in_sizes, int n_in,
                              void* d_out, int out_size, void* d_ws, size_t ws_size,
                              hipStream_t stream) {
    const float* cam  = (const float*)d_in[0];   // (4,64,64)
    const float* feat = (const float*)d_in[1];   // (4,256,64,64)
    float* out = (float*)d_out;                  // [16384 ref][1 loss]
    float* ws  = (float*)d_ws;

    float* s      = ws;                   // 16384
    float* v_part = ws + 16384;           // 512*256 = 131072
    float* v      = ws + 147456;          // 1024
    float* ob     = ws + 148480;          // 16384
    float* bmn    = ws + 164864;          // 512
    float* bmx    = ws + 165376;          // 512
    float* part   = ws + 165888;          // 64
    unsigned int* cnt = (unsigned int*)(ws + 165952);

    k_norm_vpart<<<NBLK, 256, 0, stream>>>(cam, feat, s, v_part, cnt);
    k_vreduce   <<<16,   256, 0, stream>>>(v_part, v);
    k_out       <<<NBLK, 256, 0, stream>>>(feat, s, v, ob, bmn, bmx);
    k_final     <<<64,   256, 0, stream>>>(ob, cam, bmn, bmx, out, part, cnt);
}